// Round 1
// 4483.902 us; speedup vs baseline: 2.8004x; 2.8004x over previous
//
#include <hip/hip_runtime.h>

// ---------------------------------------------------------------------------
// MyGRU_GAT on MI355X.
// R5: fence-free scan exchange — all cross-WG data moves via RELAXED
//     agent-scope atomics (sc1, LLC-coherent, no buffer_wbl2/buffer_inv).
//     Barrier = syncthreads(vmcnt drain) + relaxed flag + relaxed poll.
//     Also: U1/U2 column weights hoisted to registers, A1 prefetched at
//     phase start, r1g+r2g LLC reads issued together, last barrier skipped.
// Pipeline: detect -> prep_att -> transposes -> gat -> gemm_a1 ->
//           persistent scan -> gemm_logits -> logsoftmax fixup.
// ---------------------------------------------------------------------------

typedef unsigned short u16;
typedef unsigned long long u64;
typedef __attribute__((ext_vector_type(8))) short s16x8;
typedef __attribute__((ext_vector_type(8))) u16  u16x8;
typedef __attribute__((ext_vector_type(4))) float f32x4;

__device__ __forceinline__ float bf2f(u16 u) {
    unsigned int x = ((unsigned int)u) << 16;
    return __uint_as_float(x);
}
__device__ __forceinline__ u16 f2bf(float f) {
    unsigned int x = __float_as_uint(f);
    x = x + 0x7fffu + ((x >> 16) & 1u);   // RNE
    return (u16)(x >> 16);
}
__device__ __forceinline__ float sigmoidf_(float x) { return 1.f / (1.f + __expf(-x)); }
// dual-mode input load: m=1 -> fp32, m=0 -> bf16
__device__ __forceinline__ float ldin(const void* p, size_t i, int m) {
    return m ? ((const float*)p)[i] : bf2f(((const u16*)p)[i]);
}
__device__ __forceinline__ bool nanf_(float v) { return !(v == v); }

// ---------------- constants ----------------
#define S_SEQ 512      // B*T
#define NND   32       // nodes per subgraph
#define DIM   512
#define NHEAD 8
#define CI    1024
#define NV3   1536
#define VOC   50000
#define KWG   64       // scan workgroups
#define TSTEPS 512

// ---------------- ws offsets (bytes) ----------------
// zero region [0,20480): barrier slots, mode, flags, g1buf, g2buf, r1g, r2g, rowsum
#define OFF_BAR     0            // 64 slots, stride 64B
#define OFF_MODE    4096
#define OFF_FLAGS   4100
#define OFF_G1      4352
#define OFF_G2      8448
#define OFF_R1      12544
#define OFF_R2      14592
#define OFF_ROWSUM  16640
#define OFF_WAS     20480
#define OFF_WAD     36864
#define OFF_INP     53248            // bf16 [512][1024]
#define OFF_A1      1101824          // f32  [512][1536]
#define OFF_H2      4247552          // bf16 [512][512]
#define OFF_WST     4771840          // bf16 9x[512][512] transposed
#define OFF_WCATT   9490432          // bf16 [1536][1024]
// end = 12636160 bytes (~12.6 MB)

// ---------------------------------------------------------------------------
// detect_mode: fp32 data read as u16 has ~50% of lanes with exponent>=2.0;
// bf16 data at scale 0.02 has none.
// ---------------------------------------------------------------------------
__global__ void detect_mode(const void* X, int* mode) {
    const u16* p = (const u16*)X;
    int tid = threadIdx.x;
    int hits = 0;
    for (int i = tid; i < 1024; i += 64) {
        u16 u = p[i];
        if ((u & 0x7f80u) >= 0x4000u) hits++;
    }
    hits += __shfl_xor(hits, 1);  hits += __shfl_xor(hits, 2);
    hits += __shfl_xor(hits, 4);  hits += __shfl_xor(hits, 8);
    hits += __shfl_xor(hits, 16); hits += __shfl_xor(hits, 32);
    if (tid == 0) *mode = (hits > 8) ? 1 : 0;
}

// ---------------------------------------------------------------------------
// prep_att: WAs[d][h] = sum_k W_gat[d][h*64+k]*att_src[h][k]; same for WAd.
// ---------------------------------------------------------------------------
__global__ void prep_att(const void* __restrict__ Wgat, const void* __restrict__ asrc,
                         const void* __restrict__ adst, float* __restrict__ WAs,
                         float* __restrict__ WAd, const int* __restrict__ modep) {
    const int m = *modep;
    int id = blockIdx.x * 256 + threadIdx.x;      // 0..8191
    int which = id >> 12;
    int rem = id & 4095;
    int d = rem >> 3, h = rem & 7;
    const void* att = which ? adst : asrc;
    float sum = 0.f;
#pragma unroll 8
    for (int k = 0; k < 64; ++k)
        sum += ldin(Wgat, d * 512 + h * 64 + k, m) * ldin(att, h * 64 + k, m);
    (which ? WAd : WAs)[d * 8 + h] = sum;
}

// ---------------------------------------------------------------------------
// transposes -> bf16. tile 32x32, 256 threads.
// ---------------------------------------------------------------------------
struct Ptrs9 { const void* p[9]; };
__global__ void transpose9(Ptrs9 ps, u16* __restrict__ dst, const int* __restrict__ modep) {
    const int m = *modep;
    __shared__ u16 tile[32][33];
    const void* src = ps.p[blockIdx.z];
    u16* d = dst + (size_t)blockIdx.z * 262144;
    int c0 = blockIdx.x * 32, r0 = blockIdx.y * 32;
    int tx = threadIdx.x & 31, ty = threadIdx.x >> 5;
#pragma unroll
    for (int i = 0; i < 32; i += 8)
        tile[ty + i][tx] = f2bf(ldin(src, (size_t)(r0 + ty + i) * 512 + c0 + tx, m));
    __syncthreads();
#pragma unroll
    for (int i = 0; i < 32; i += 8)
        d[(size_t)(c0 + ty + i) * 512 + r0 + tx] = tile[tx][ty + i];
}

struct Ptrs3 { const void* p[3]; };
__global__ void transpose3(Ptrs3 ps, u16* __restrict__ dst, const int* __restrict__ modep) {
    // [1024][512] -> [512][1024]
    const int m = *modep;
    __shared__ u16 tile[32][33];
    const void* src = ps.p[blockIdx.z];
    u16* d = dst + (size_t)blockIdx.z * 524288;
    int c0 = blockIdx.x * 32, r0 = blockIdx.y * 32;
    int tx = threadIdx.x & 31, ty = threadIdx.x >> 5;
#pragma unroll
    for (int i = 0; i < 32; i += 8)
        tile[ty + i][tx] = f2bf(ldin(src, (size_t)(r0 + ty + i) * 512 + c0 + tx, m));
    __syncthreads();
#pragma unroll
    for (int i = 0; i < 32; i += 8)
        d[(size_t)(c0 + ty + i) * 1024 + r0 + tx] = tile[tx][ty + i];
}

// ---------------------------------------------------------------------------
// GAT: one WG per subgraph; only node-0 output is needed.
// ---------------------------------------------------------------------------
__global__ __launch_bounds__(256) void gat_kernel(
    const int* __restrict__ xidx, const int* __restrict__ eidx,
    const void* __restrict__ X, const void* __restrict__ Wgat,
    const float* __restrict__ WAs, const float* __restrict__ WAd,
    const void* __restrict__ bgat, u16* __restrict__ inp,
    const int* __restrict__ modep, int* __restrict__ flags) {
    const int m = *modep;
    int s = blockIdx.x, tid = threadIdx.x;
    __shared__ int idxL[NND];
    __shared__ int srcL[260];
    __shared__ int nsrcL;
    __shared__ float asL[NND][NHEAD];
    __shared__ float ad0[NHEAD];
    __shared__ float scoresL[257 * NHEAD];
    __shared__ float denL[NHEAD];
    __shared__ float xbL[NHEAD][DIM];

    if (tid < NND) idxL[tid] = xidx[s * NND + tid];
    if (tid == 0) nsrcL = 0;
    __syncthreads();

    { // a_s for all nodes; a_d for node 0
        int n = tid >> 3, h = tid & 7;
        size_t xoff = (size_t)idxL[n] * DIM;
        float acc = 0.f, accd = 0.f;
        for (int d = 0; d < DIM; ++d) {
            float xv = ldin(X, xoff + d, m);
            acc  += xv * WAs[d * 8 + h];
            accd += xv * WAd[d * 8 + h];
        }
        asL[n][h] = acc;
        if (n == 0) ad0[h] = accd;
    }
    { // build src list for dst==0 (+ self loop)
        int dstn = eidx[s * 512 + 256 + tid];
        if (dstn == 0) {
            int p = atomicAdd(&nsrcL, 1);
            srcL[p] = eidx[s * 512 + tid];
        }
        if (tid == 0) { int p = atomicAdd(&nsrcL, 1); srcL[p] = 0; }
    }
    __syncthreads();
    int nsrc = nsrcL;

    for (int p = tid; p < nsrc * NHEAD; p += 256) {
        int le = p >> 3, h = p & 7;
        float e = asL[srcL[le]][h] + ad0[h];
        e = (e >= 0.f) ? e : 0.2f * e;           // leaky_relu 0.2
        scoresL[le * 8 + h] = e;
    }
    __syncthreads();
    if (tid < NHEAD) {
        int h = tid;
        float mx = -1e30f;
        for (int le = 0; le < nsrc; ++le) mx = fmaxf(mx, scoresL[le * 8 + h]);
        float den = 0.f;
        for (int le = 0; le < nsrc; ++le) {
            float ex = __expf(scoresL[le * 8 + h] - mx);
            scoresL[le * 8 + h] = ex;
            den += ex;
        }
        denL[h] = den + 1e-16f;
    }
    __syncthreads();
    // xb[h][d] = sum_le alpha(le,h) * X[src_le][d]
    for (int p = tid; p < NHEAD * DIM; p += 256) {
        int d = p & 511, h = p >> 9;
        float acc = 0.f;
        for (int le = 0; le < nsrc; ++le)
            acc += scoresL[le * 8 + h] * ldin(X, (size_t)idxL[srcL[le]] * DIM + d, m);
        xbL[h][d] = acc / denL[h];
    }
    __syncthreads();
    // out0[c] = sum_d xb[c>>6][d]*Wgat[d][c] + b_gat[c]; write inp row
    for (int c = tid; c < DIM; c += 256) {
        int h = c >> 6;
        float acc = 0.f;
        for (int d = 0; d < DIM; ++d)
            acc += xbL[h][d] * ldin(Wgat, d * 512 + c, m);
        acc += ldin(bgat, c, m);
        float xv = ldin(X, (size_t)idxL[0] * DIM + c, m);
        if (nanf_(acc)) { atomicOr(flags, 1); acc = 0.f; }
        if (nanf_(xv))  { atomicOr(flags, 1); xv  = 0.f; }
        inp[(size_t)s * CI + DIM + c] = f2bf(acc);
        inp[(size_t)s * CI + c] = f2bf(xv);
    }
}

// ---------------------------------------------------------------------------
// MFMA GEMM #1: A1 = inp @ [Wz1|Wr1|W1] (+ bW1+bU1 on W1 part). fp32 out.
// ---------------------------------------------------------------------------
__global__ __launch_bounds__(256) void gemm_a1(
    const u16* __restrict__ A, const u16* __restrict__ BT,
    const void* __restrict__ bW1, const void* __restrict__ bU1,
    float* __restrict__ C, const int* __restrict__ modep, int* __restrict__ flags) {
    const int m = *modep;
    const int K = CI;
    int tid = threadIdx.x, wave = tid >> 6, lane = tid & 63;
    int mw = wave & 1, nw = wave >> 1, l15 = lane & 15, q = lane >> 4;
    int mbase = blockIdx.y * 64 + mw * 32;
    int nbase = blockIdx.x * 128 + nw * 64;
    f32x4 acc[2][4];
#pragma unroll
    for (int mi = 0; mi < 2; ++mi)
#pragma unroll
        for (int ni = 0; ni < 4; ++ni) acc[mi][ni] = (f32x4){0.f, 0.f, 0.f, 0.f};
    for (int k0 = 0; k0 < K; k0 += 32) {
        s16x8 a[2], b[4];
#pragma unroll
        for (int mi = 0; mi < 2; ++mi)
            a[mi] = *(const s16x8*)(A + (size_t)(mbase + mi * 16 + l15) * K + k0 + q * 8);
#pragma unroll
        for (int ni = 0; ni < 4; ++ni)
            b[ni] = *(const s16x8*)(BT + (size_t)(nbase + ni * 16 + l15) * K + k0 + q * 8);
#pragma unroll
        for (int mi = 0; mi < 2; ++mi)
#pragma unroll
            for (int ni = 0; ni < 4; ++ni)
                acc[mi][ni] = __builtin_amdgcn_mfma_f32_16x16x32_bf16(a[mi], b[ni], acc[mi][ni], 0, 0, 0);
    }
#pragma unroll
    for (int mi = 0; mi < 2; ++mi)
#pragma unroll
        for (int r = 0; r < 4; ++r) {
            int row = mbase + mi * 16 + q * 4 + r;
#pragma unroll
            for (int ni = 0; ni < 4; ++ni) {
                int col = nbase + ni * 16 + l15;
                float v = acc[mi][ni][r];
                if (col >= 1024) v += ldin(bW1, col - 1024, m) + ldin(bU1, col - 1024, m);
                if (nanf_(v)) { atomicOr(flags, 2); v = 0.f; }
                C[(size_t)row * NV3 + col] = v;
            }
        }
}

// ---------------------------------------------------------------------------
// Persistent GRU scan. 64 WGs x 256 threads. 2 sync slots per step.
// R5: all cross-WG data via RELAXED agent atomics (sc1 -> LLC coherence
// point); no threadfence / no acquire-release cache maintenance anywhere.
// ---------------------------------------------------------------------------
#define WSTRIDE 520

__global__ __launch_bounds__(256) void scan_kernel(
    const float* __restrict__ A1, const u16* __restrict__ wsT,
    const void* __restrict__ bW2, const void* __restrict__ bU2,
    float* __restrict__ g1buf, float* __restrict__ g2buf,
    float* __restrict__ r1g, float* __restrict__ r2g,
    u16* __restrict__ H2, int* __restrict__ bar,
    const int* __restrict__ modep, int* __restrict__ flags) {
    const int m_ = *modep;
    const int wg = blockIdx.x;
    const int tid = threadIdx.x;
    const int jj = tid & 7, g = tid >> 3;
    const int j0 = wg * 8;
    const int lane = tid & 63, wave = tid >> 6;

    __shared__ u16 wL[7 * 8 * WSTRIDE];
    __shared__ float g1c[512], g2c[512], rbuf[512];
    __shared__ float red[4][7][8];
    __shared__ float z1loc[8], z2loc[8], pW2loc[8], bsum[8];

    {
        int jj2 = tid >> 5, i2 = (tid & 31) * 16;
        for (int m = 0; m < 7; ++m) {
            const u16* src = wsT + (size_t)m * 262144 + (size_t)(j0 + jj2) * 512 + i2;
            u16* dstp = &wL[(m * 8 + jj2) * WSTRIDE + i2];
            ((u16x8*)dstp)[0] = ((const u16x8*)src)[0];
            ((u16x8*)dstp)[1] = ((const u16x8*)src)[1];
        }
        if (tid < 8) bsum[tid] = ldin(bW2, j0 + tid, m_) + ldin(bU2, j0 + tid, m_);
    }
    // loop-invariant U1/U2 column fragments -> registers (were re-read from
    // global every odd phase; identical data every step)
    const u16* u1col = wsT + (size_t)7 * 262144 + (size_t)(j0 + jj) * 512;
    const u16* u2col = wsT + (size_t)8 * 262144 + (size_t)(j0 + jj) * 512;
    const u16x8 u1w0 = *(const u16x8*)(u1col + g * 16);
    const u16x8 u1w1 = *(const u16x8*)(u1col + g * 16 + 8);
    const u16x8 u2w0 = *(const u16x8*)(u2col + g * 16);
    const u16x8 u2w1 = *(const u16x8*)(u2col + g * 16 + 8);
    __syncthreads();

    float awk = 0.f;                 // A1 W1-part value, carried even->odd phase
    int epoch = 1;
    for (int q_ = 0; q_ < 2 * TSTEPS + 2; ++q_) {
        int t = q_ >> 1;
        if (!(q_ & 1)) {
            // prefetch this step's A1 values early (independent of exchange)
            float azv = 0.f, arv = 0.f;
            if (tid < 8 && t < TSTEPS) {
                const float* a1p = A1 + (size_t)t * NV3 + j0 + tid;
                azv = a1p[0];
                arv = a1p[512];
                awk = a1p[1024];
            }
            { // pull h1/h2 broadcast from LLC (sc1, bypasses stale L2)
                u64* g1p = (u64*)(g1buf + (t & 1) * 512);
                u64* g2p = (u64*)(g2buf + ((t + 1) & 1) * 512);
                u64 v1 = __hip_atomic_load(g1p + tid, __ATOMIC_RELAXED, __HIP_MEMORY_SCOPE_AGENT);
                u64 v2 = __hip_atomic_load(g2p + tid, __ATOMIC_RELAXED, __HIP_MEMORY_SCOPE_AGENT);
                ((u64*)g1c)[tid] = v1;
                ((u64*)g2c)[tid] = v2;
            }
            __syncthreads();
            float p[7] = {0.f, 0.f, 0.f, 0.f, 0.f, 0.f, 0.f};
#pragma unroll
            for (int u = 0; u < 16; ++u) {
                int i = g * 16 + u;
                float x1 = g1c[i], x2 = g2c[i];
                p[0] = fmaf(x1, bf2f(wL[(0 * 8 + jj) * WSTRIDE + i]), p[0]);  // Uz1
                p[1] = fmaf(x1, bf2f(wL[(1 * 8 + jj) * WSTRIDE + i]), p[1]);  // Ur1
                p[2] = fmaf(x1, bf2f(wL[(2 * 8 + jj) * WSTRIDE + i]), p[2]);  // Wz2
                p[3] = fmaf(x1, bf2f(wL[(3 * 8 + jj) * WSTRIDE + i]), p[3]);  // Wr2
                p[4] = fmaf(x1, bf2f(wL[(4 * 8 + jj) * WSTRIDE + i]), p[4]);  // W2
                p[5] = fmaf(x2, bf2f(wL[(5 * 8 + jj) * WSTRIDE + i]), p[5]);  // Uz2
                p[6] = fmaf(x2, bf2f(wL[(6 * 8 + jj) * WSTRIDE + i]), p[6]);  // Ur2
            }
#pragma unroll
            for (int m = 0; m < 7; ++m) {
                float v = p[m];
                v += __shfl_xor(v, 8); v += __shfl_xor(v, 16); v += __shfl_xor(v, 32);
                if (lane < 8) red[wave][m][lane] = v;
            }
            __syncthreads();
            if (tid < 8) {
                float s0 = red[0][0][tid] + red[1][0][tid] + red[2][0][tid] + red[3][0][tid];
                float s1 = red[0][1][tid] + red[1][1][tid] + red[2][1][tid] + red[3][1][tid];
                float s2 = red[0][2][tid] + red[1][2][tid] + red[2][2][tid] + red[3][2][tid];
                float s3 = red[0][3][tid] + red[1][3][tid] + red[2][3][tid] + red[3][3][tid];
                float s4 = red[0][4][tid] + red[1][4][tid] + red[2][4][tid] + red[3][4][tid];
                float s5 = red[0][5][tid] + red[1][5][tid] + red[2][5][tid] + red[3][5][tid];
                float s6 = red[0][6][tid] + red[1][6][tid] + red[2][6][tid] + red[3][6][tid];
                int j = j0 + tid;
                if (t < TSTEPS) {
                    z1loc[tid] = sigmoidf_(azv + s0);
                    __hip_atomic_store(&r1g[j], sigmoidf_(arv + s1),
                                       __ATOMIC_RELAXED, __HIP_MEMORY_SCOPE_AGENT);
                }
                if (t >= 1) {
                    z2loc[tid] = sigmoidf_(s2 + s5);
                    __hip_atomic_store(&r2g[j], sigmoidf_(s3 + s6),
                                       __ATOMIC_RELAXED, __HIP_MEMORY_SCOPE_AGENT);
                    pW2loc[tid] = s4;
                }
            }
        } else {
            // issue both r-gate LLC reads together (one round-trip, not two)
            u64 rv1 = 0ull, rv2 = 0ull;
            if (t < TSTEPS)
                rv1 = __hip_atomic_load((u64*)r1g + tid, __ATOMIC_RELAXED, __HIP_MEMORY_SCOPE_AGENT);
            if (t >= 1)
                rv2 = __hip_atomic_load((u64*)r2g + tid, __ATOMIC_RELAXED, __HIP_MEMORY_SCOPE_AGENT);
            if (t < TSTEPS) {
                ((u64*)rbuf)[tid] = rv1;
                __syncthreads();
                float pa = 0.f;
#pragma unroll
                for (int u = 0; u < 8; ++u) {
                    int i = g * 16 + u;
                    pa = fmaf(rbuf[i] * g1c[i], bf2f(u1w0[u]), pa);
                }
#pragma unroll
                for (int u = 0; u < 8; ++u) {
                    int i = g * 16 + 8 + u;
                    pa = fmaf(rbuf[i] * g1c[i], bf2f(u1w1[u]), pa);
                }
                pa += __shfl_xor(pa, 8); pa += __shfl_xor(pa, 16); pa += __shfl_xor(pa, 32);
                if (lane < 8) red[wave][0][lane] = pa;
                __syncthreads();
                if (tid < 8) {
                    float s = red[0][0][tid] + red[1][0][tid] + red[2][0][tid] + red[3][0][tid];
                    int j = j0 + tid;
                    float ht1 = tanhf(awk + s);
                    float z = z1loc[tid], g1v = g1c[j];
                    float g1n = z * ht1 + (1.f - z) * g1v;
                    if (nanf_(g1n)) { atomicOr(flags, 4); g1n = 0.f; }
                    __hip_atomic_store(&g1buf[((t + 1) & 1) * 512 + j], g1n,
                                       __ATOMIC_RELAXED, __HIP_MEMORY_SCOPE_AGENT);
                }
            }
            if (t >= 1) {
                __syncthreads();
                ((u64*)rbuf)[tid] = rv2;
                __syncthreads();
                float pa = 0.f;
#pragma unroll
                for (int u = 0; u < 8; ++u) {
                    int i = g * 16 + u;
                    pa = fmaf(rbuf[i] * g2c[i], bf2f(u2w0[u]), pa);
                }
#pragma unroll
                for (int u = 0; u < 8; ++u) {
                    int i = g * 16 + 8 + u;
                    pa = fmaf(rbuf[i] * g2c[i], bf2f(u2w1[u]), pa);
                }
                pa += __shfl_xor(pa, 8); pa += __shfl_xor(pa, 16); pa += __shfl_xor(pa, 32);
                if (lane < 8) red[wave][1][lane] = pa;
                __syncthreads();
                if (tid < 8) {
                    float s = red[0][1][tid] + red[1][1][tid] + red[2][1][tid] + red[3][1][tid];
                    int j = j0 + tid;
                    float ht2 = tanhf(pW2loc[tid] + bsum[tid] + s);
                    float z = z2loc[tid], g2v = g2c[j];
                    float g2n = z * ht2 + (1.f - z) * g2v;
                    if (nanf_(g2n)) { atomicOr(flags, 4); g2n = 0.f; }
                    __hip_atomic_store(&g2buf[(t & 1) * 512 + j], g2n,
                                       __ATOMIC_RELAXED, __HIP_MEMORY_SCOPE_AGENT);
                    H2[(size_t)(t - 1) * 512 + j] = f2bf(g2n);   // next-kernel consumer
                }
            }
        }
        if (q_ == 2 * TSTEPS + 1) break;   // last iteration: no barrier needed
        // ---- fence-free flag barrier across the 64 WGs ----
        // All exchanged stores are sc1 (complete at LLC). syncthreads drains
        // each wave's vmcnt; explicit waitcnt keeps ordering even if the
        // compiler elides it. Flag store + poll are RELAXED: no buffer_inv,
        // no buffer_wbl2 in the loop.
        asm volatile("" ::: "memory");
        __syncthreads();
        asm volatile("s_waitcnt vmcnt(0)" ::: "memory");
        if (tid == 0)
            __hip_atomic_store(&bar[wg * 16], epoch, __ATOMIC_RELAXED, __HIP_MEMORY_SCOPE_AGENT);
        if (tid < 64) {
            for (;;) {
                int v = __hip_atomic_load(&bar[tid * 16], __ATOMIC_RELAXED, __HIP_MEMORY_SCOPE_AGENT);
                if (__all(v >= epoch)) break;
                __builtin_amdgcn_s_sleep(1);
            }
        }
        asm volatile("" ::: "memory");
        __syncthreads();
        ++epoch;
    }
}

// ---------------------------------------------------------------------------
// MFMA GEMM #2: logits = H2 @ Wg + bg -> d_out (mode dtype), + row exp-sums.
// ---------------------------------------------------------------------------
__global__ __launch_bounds__(256) void gemm_logits(
    const u16* __restrict__ H2, const void* __restrict__ Wg,
    const void* __restrict__ bg, void* __restrict__ out,
    float* __restrict__ rowsum, const int* __restrict__ modep, int* __restrict__ flags) {
    const int m = *modep;
    const int K = DIM;
    int tid = threadIdx.x, wave = tid >> 6, lane = tid & 63;
    int mw = wave & 1, nw = wave >> 1, l15 = lane & 15, q = lane >> 4;
    int mbase = blockIdx.y * 64 + mw * 32;
    int nbase = blockIdx.x * 128 + nw * 64;
    f32x4 acc[2][4];
#pragma unroll
    for (int mi = 0; mi < 2; ++mi)
#pragma unroll
        for (int ni = 0; ni < 4; ++ni) acc[mi][ni] = (f32x4){0.f, 0.f, 0.f, 0.f};
    for (int k0 = 0; k0 < K; k0 += 32) {
        s16x8 a[2], b[4];
#pragma unroll
        for (int mi = 0; mi < 2; ++mi)
            a[mi] = *(const s16x8*)(H2 + (size_t)(mbase + mi * 16 + l15) * K + k0 + q * 8);
#pragma unroll
        for (int ni = 0; ni < 4; ++ni) {
            int n = nbase + ni * 16 + l15;
            if (n >= VOC) n = VOC - 1;
            size_t kb = (size_t)(k0 + q * 8) * VOC + n;
#pragma unroll
            for (int j = 0; j < 8; ++j) b[ni][j] = (short)f2bf(ldin(Wg, kb + (size_t)j * VOC, m));
        }
#pragma unroll
        for (int mi = 0; mi < 2; ++mi)
#pragma unroll
            for (int ni = 0; ni < 4; ++ni)
                acc[mi][ni] = __builtin_amdgcn_mfma_f32_16x16x32_bf16(a[mi], b[ni], acc[mi][ni], 0, 0, 0);
    }
    __shared__ float lds_rows[64];
    if (tid < 64) lds_rows[tid] = 0.f;
    __syncthreads();
#pragma unroll
    for (int mi = 0; mi < 2; ++mi)
#pragma unroll
        for (int r = 0; r < 4; ++r) {
            int row = mbase + mi * 16 + q * 4 + r;
            float esum = 0.f;
#pragma unroll
            for (int ni = 0; ni < 4; ++ni) {
                int col = nbase + ni * 16 + l15;
                float v = acc[mi][ni][r];
                if (col < VOC) {
                    v += ldin(bg, col, m);
                    if (nanf_(v)) { atomicOr(flags, 8); v = 0.f; }
                    if (m) ((float*)out)[(size_t)row * VOC + col] = v;
                    else   ((u16*)out)[(size_t)row * VOC + col] = f2bf(v);
                    esum += __expf(v);
                }
            }
            esum += __shfl_xor(esum, 1); esum += __shfl_xor(esum, 2);
            esum += __shfl_xor(esum, 4); esum += __shfl_xor(esum, 8);
            if (l15 == 0) atomicAdd(&lds_rows[row - blockIdx.y * 64], esum);
        }
    __syncthreads();
    if (tid < 64) atomicAdd(&rowsum[blockIdx.y * 64 + tid], lds_rows[tid]);
}

// ---------------------------------------------------------------------------
// in-place: out = logit - log(rowsum[row]); out[0] += 1000*stage if NaN seen.
// ---------------------------------------------------------------------------
__global__ __launch_bounds__(256) void logsoftmax_fix(void* __restrict__ out,
                                                      const float* __restrict__ rowsum,
                                                      const int* __restrict__ modep,
                                                      int* __restrict__ flags) {
    const int m = *modep;
    int row = blockIdx.y;
    int c0 = blockIdx.x * 2048 + threadIdx.x * 8;
    if (c0 >= VOC) return;
    float rs = rowsum[row];
    float ls = logf(rs);
    if (nanf_(ls) || !(rs > 0.f)) { atomicOr(flags, 16); ls = 0.f; }
    float sentinel = 0.f;
    if (row == 0 && c0 == 0) {
        int f = *flags;
        if (f) sentinel = 1000.f * (float)__ffs(f);
    }
    size_t base = (size_t)row * VOC + c0;
    if (m) {
        float* o = (float*)out;
        int lim = (c0 + 8 <= VOC) ? 8 : (VOC - c0);
        for (int i = 0; i < lim; ++i) {
            float v = o[base + i] - ls;
            if (i == 0) v += sentinel;
            o[base + i] = v;
        }
    } else {
        u16* o = (u16*)out;
        int lim = (c0 + 8 <= VOC) ? 8 : (VOC - c0);
        for (int i = 0; i < lim; ++i) {
            float v = bf2f(o[base + i]) - ls;
            if (i == 0) v += sentinel;
            o[base + i] = f2bf(v);
        }
    }
}

// ---------------------------------------------------------------------------
extern "C" void kernel_launch(void* const* d_in, const int* in_sizes, int n_in,
                              void* d_out, int out_size, void* d_ws, size_t ws_size,
                              hipStream_t stream) {
    const int* xidx = (const int*)d_in[0];
    const int* eidx = (const int*)d_in[1];
    const void* X    = d_in[2];
    const void* Wgat = d_in[3];
    const void* asrc = d_in[4];
    const void* adst = d_in[5];
    const void* bgat = d_in[6];
    const void* Wz1  = d_in[7];
    const void* Uz1  = d_in[8];
    const void* Wr1  = d_in[9];
    const void* Ur1  = d_in[10];
    const void* W1   = d_in[11];
    const void* bW1  = d_in[12];
    const void* U1   = d_in[13];
    const void* bU1  = d_in[14];
    const void* Wz2  = d_in[15];
    const void* Uz2  = d_in[16];
    const void* Wr2  = d_in[17];
    const void* Ur2  = d_in[18];
    const void* W2   = d_in[19];
    const void* bW2  = d_in[20];
    const void* U2   = d_in[21];
    const void* bU2  = d_in[22];
    const void* Wg   = d_in[23];
    const void* bg   = d_in[24];

    char* ws = (char*)d_ws;
    int*   bar    = (int*)(ws + OFF_BAR);
    int*   modep  = (int*)(ws + OFF_MODE);
    int*   flags  = (int*)(ws + OFF_FLAGS);
    float* g1buf  = (float*)(ws + OFF_G1);
    float* g2buf  = (float*)(ws + OFF_G2);
    float* r1g    = (float*)(ws + OFF_R1);
    float* r2g    = (float*)(ws + OFF_R2);
    float* rowsum = (float*)(ws + OFF_ROWSUM);
    float* WAs    = (float*)(ws + OFF_WAS);
    float* WAd    = (float*)(ws + OFF_WAD);
    u16*   inp    = (u16*)(ws + OFF_INP);
    float* A1     = (float*)(ws + OFF_A1);
    u16*   H2     = (u16*)(ws + OFF_H2);
    u16*   wsT    = (u16*)(ws + OFF_WST);
    u16*   WcatT  = (u16*)(ws + OFF_WCATT);

    hipMemsetAsync(ws, 0, 20480, stream);

    detect_mode<<<1, 64, 0, stream>>>(X, modep);

    prep_att<<<32, 256, 0, stream>>>(Wgat, asrc, adst, WAs, WAd, modep);

    Ptrs9 p9; // order: Uz1,Ur1,Wz2,Wr2,W2,Uz2,Ur2,U1,U2
    p9.p[0] = Uz1; p9.p[1] = Ur1; p9.p[2] = Wz2; p9.p[3] = Wr2; p9.p[4] = W2;
    p9.p[5] = Uz2; p9.p[6] = Ur2; p9.p[7] = U1;  p9.p[8] = U2;
    transpose9<<<dim3(16, 16, 9), 256, 0, stream>>>(p9, wsT, modep);

    Ptrs3 p3; p3.p[0] = Wz1; p3.p[1] = Wr1; p3.p[2] = W1;
    transpose3<<<dim3(16, 32, 3), 256, 0, stream>>>(p3, WcatT, modep);

    gat_kernel<<<S_SEQ, 256, 0, stream>>>(xidx, eidx, X, Wgat, WAs, WAd, bgat, inp, modep, flags);

    gemm_a1<<<dim3(NV3 / 128, S_SEQ / 64), 256, 0, stream>>>(inp, WcatT, bW1, bU1, A1, modep, flags);

    scan_kernel<<<KWG, 256, 0, stream>>>(A1, wsT, bW2, bU2, g1buf, g2buf, r1g, r2g, H2, bar, modep, flags);

    gemm_logits<<<dim3((VOC + 127) / 128, S_SEQ / 64), 256, 0, stream>>>(H2, Wg, bg, d_out, rowsum, modep, flags);

    logsoftmax_fix<<<dim3(25, S_SEQ), 256, 0, stream>>>(d_out, rowsum, modep, flags);
}

// Round 2
// 3355.609 us; speedup vs baseline: 3.7420x; 1.3362x over previous
//
#include <hip/hip_runtime.h>

// ---------------------------------------------------------------------------
// MyGRU_GAT on MI355X.
// R6: epoch-tagged data exchange in the scan — every cross-WG float is a
//     u64 {epoch,f32} relaxed agent atomic; consumers poll directly on the
//     data (no flag barrier, no vmcnt drain). Weights hoisted from LDS to
//     registers (loop-invariant): wL deleted, bank conflicts gone.
// Pipeline: detect -> prep_att -> transposes -> gat -> gemm_a1 ->
//           persistent scan -> gemm_logits -> logsoftmax fixup.
// ---------------------------------------------------------------------------

typedef unsigned short u16;
typedef unsigned long long u64;
typedef __attribute__((ext_vector_type(8))) short s16x8;
typedef __attribute__((ext_vector_type(8))) u16  u16x8;
typedef __attribute__((ext_vector_type(4))) float f32x4;

__device__ __forceinline__ float bf2f(u16 u) {
    unsigned int x = ((unsigned int)u) << 16;
    return __uint_as_float(x);
}
__device__ __forceinline__ u16 f2bf(float f) {
    unsigned int x = __float_as_uint(f);
    x = x + 0x7fffu + ((x >> 16) & 1u);   // RNE
    return (u16)(x >> 16);
}
__device__ __forceinline__ float sigmoidf_(float x) { return 1.f / (1.f + __expf(-x)); }
// dual-mode input load: m=1 -> fp32, m=0 -> bf16
__device__ __forceinline__ float ldin(const void* p, size_t i, int m) {
    return m ? ((const float*)p)[i] : bf2f(((const u16*)p)[i]);
}
__device__ __forceinline__ bool nanf_(float v) { return !(v == v); }

// tagged-exchange helpers: u64 = {epoch:32 | f32 bits:32}
__device__ __forceinline__ u64 packtag(float v, unsigned int e) {
    return ((u64)e << 32) | (u64)__float_as_uint(v);
}
__device__ __forceinline__ float tagval(u64 x) { return __uint_as_float((unsigned int)x); }
__device__ __forceinline__ unsigned int tagof(u64 x) { return (unsigned int)(x >> 32); }

#define AL64(p) __hip_atomic_load((p), __ATOMIC_RELAXED, __HIP_MEMORY_SCOPE_AGENT)
#define AS64(p, v) __hip_atomic_store((p), (v), __ATOMIC_RELAXED, __HIP_MEMORY_SCOPE_AGENT)

// ---------------- constants ----------------
#define S_SEQ 512      // B*T
#define NND   32       // nodes per subgraph
#define DIM   512
#define NHEAD 8
#define CI    1024
#define NV3   1536
#define VOC   50000
#define KWG   64       // scan workgroups
#define TSTEPS 512

// ---------------- ws offsets (bytes) ----------------
// zero region [0,28672): mode, flags, rowsum, tagged g1/g2/r1/r2
#define OFF_MODE    0
#define OFF_FLAGS   4
#define OFF_ROWSUM  256              // f32[512]
#define OFF_G1      4096             // u64[2][512] tagged
#define OFF_G2      12288            // u64[2][512] tagged
#define OFF_R1      20480            // u64[512] tagged
#define OFF_R2      24576            // u64[512] tagged
#define ZERO_BYTES  28672
#define OFF_WAS     28672
#define OFF_WAD     45056
#define OFF_INP     61440            // bf16 [512][1024]
#define OFF_A1      1110016          // f32  [512][1536]
#define OFF_H2      4255744          // bf16 [512][512]
#define OFF_WST     4780032          // bf16 9x[512][512] transposed
#define OFF_WCATT   9498624          // bf16 [1536][1024]
// end = 12644352 bytes (~12.6 MB)

// ---------------------------------------------------------------------------
// detect_mode: fp32 data read as u16 has ~50% of lanes with exponent>=2.0;
// bf16 data at scale 0.02 has none.
// ---------------------------------------------------------------------------
__global__ void detect_mode(const void* X, int* mode) {
    const u16* p = (const u16*)X;
    int tid = threadIdx.x;
    int hits = 0;
    for (int i = tid; i < 1024; i += 64) {
        u16 u = p[i];
        if ((u & 0x7f80u) >= 0x4000u) hits++;
    }
    hits += __shfl_xor(hits, 1);  hits += __shfl_xor(hits, 2);
    hits += __shfl_xor(hits, 4);  hits += __shfl_xor(hits, 8);
    hits += __shfl_xor(hits, 16); hits += __shfl_xor(hits, 32);
    if (tid == 0) *mode = (hits > 8) ? 1 : 0;
}

// ---------------------------------------------------------------------------
// prep_att: WAs[d][h] = sum_k W_gat[d][h*64+k]*att_src[h][k]; same for WAd.
// ---------------------------------------------------------------------------
__global__ void prep_att(const void* __restrict__ Wgat, const void* __restrict__ asrc,
                         const void* __restrict__ adst, float* __restrict__ WAs,
                         float* __restrict__ WAd, const int* __restrict__ modep) {
    const int m = *modep;
    int id = blockIdx.x * 256 + threadIdx.x;      // 0..8191
    int which = id >> 12;
    int rem = id & 4095;
    int d = rem >> 3, h = rem & 7;
    const void* att = which ? adst : asrc;
    float sum = 0.f;
#pragma unroll 8
    for (int k = 0; k < 64; ++k)
        sum += ldin(Wgat, d * 512 + h * 64 + k, m) * ldin(att, h * 64 + k, m);
    (which ? WAd : WAs)[d * 8 + h] = sum;
}

// ---------------------------------------------------------------------------
// transposes -> bf16. tile 32x32, 256 threads.
// ---------------------------------------------------------------------------
struct Ptrs9 { const void* p[9]; };
__global__ void transpose9(Ptrs9 ps, u16* __restrict__ dst, const int* __restrict__ modep) {
    const int m = *modep;
    __shared__ u16 tile[32][33];
    const void* src = ps.p[blockIdx.z];
    u16* d = dst + (size_t)blockIdx.z * 262144;
    int c0 = blockIdx.x * 32, r0 = blockIdx.y * 32;
    int tx = threadIdx.x & 31, ty = threadIdx.x >> 5;
#pragma unroll
    for (int i = 0; i < 32; i += 8)
        tile[ty + i][tx] = f2bf(ldin(src, (size_t)(r0 + ty + i) * 512 + c0 + tx, m));
    __syncthreads();
#pragma unroll
    for (int i = 0; i < 32; i += 8)
        d[(size_t)(c0 + ty + i) * 512 + r0 + tx] = tile[tx][ty + i];
}

struct Ptrs3 { const void* p[3]; };
__global__ void transpose3(Ptrs3 ps, u16* __restrict__ dst, const int* __restrict__ modep) {
    // [1024][512] -> [512][1024]
    const int m = *modep;
    __shared__ u16 tile[32][33];
    const void* src = ps.p[blockIdx.z];
    u16* d = dst + (size_t)blockIdx.z * 524288;
    int c0 = blockIdx.x * 32, r0 = blockIdx.y * 32;
    int tx = threadIdx.x & 31, ty = threadIdx.x >> 5;
#pragma unroll
    for (int i = 0; i < 32; i += 8)
        tile[ty + i][tx] = f2bf(ldin(src, (size_t)(r0 + ty + i) * 512 + c0 + tx, m));
    __syncthreads();
#pragma unroll
    for (int i = 0; i < 32; i += 8)
        d[(size_t)(c0 + ty + i) * 1024 + r0 + tx] = tile[tx][ty + i];
}

// ---------------------------------------------------------------------------
// GAT: one WG per subgraph; only node-0 output is needed.
// ---------------------------------------------------------------------------
__global__ __launch_bounds__(256) void gat_kernel(
    const int* __restrict__ xidx, const int* __restrict__ eidx,
    const void* __restrict__ X, const void* __restrict__ Wgat,
    const float* __restrict__ WAs, const float* __restrict__ WAd,
    const void* __restrict__ bgat, u16* __restrict__ inp,
    const int* __restrict__ modep, int* __restrict__ flags) {
    const int m = *modep;
    int s = blockIdx.x, tid = threadIdx.x;
    __shared__ int idxL[NND];
    __shared__ int srcL[260];
    __shared__ int nsrcL;
    __shared__ float asL[NND][NHEAD];
    __shared__ float ad0[NHEAD];
    __shared__ float scoresL[257 * NHEAD];
    __shared__ float denL[NHEAD];
    __shared__ float xbL[NHEAD][DIM];

    if (tid < NND) idxL[tid] = xidx[s * NND + tid];
    if (tid == 0) nsrcL = 0;
    __syncthreads();

    { // a_s for all nodes; a_d for node 0
        int n = tid >> 3, h = tid & 7;
        size_t xoff = (size_t)idxL[n] * DIM;
        float acc = 0.f, accd = 0.f;
        for (int d = 0; d < DIM; ++d) {
            float xv = ldin(X, xoff + d, m);
            acc  += xv * WAs[d * 8 + h];
            accd += xv * WAd[d * 8 + h];
        }
        asL[n][h] = acc;
        if (n == 0) ad0[h] = accd;
    }
    { // build src list for dst==0 (+ self loop)
        int dstn = eidx[s * 512 + 256 + tid];
        if (dstn == 0) {
            int p = atomicAdd(&nsrcL, 1);
            srcL[p] = eidx[s * 512 + tid];
        }
        if (tid == 0) { int p = atomicAdd(&nsrcL, 1); srcL[p] = 0; }
    }
    __syncthreads();
    int nsrc = nsrcL;

    for (int p = tid; p < nsrc * NHEAD; p += 256) {
        int le = p >> 3, h = p & 7;
        float e = asL[srcL[le]][h] + ad0[h];
        e = (e >= 0.f) ? e : 0.2f * e;           // leaky_relu 0.2
        scoresL[le * 8 + h] = e;
    }
    __syncthreads();
    if (tid < NHEAD) {
        int h = tid;
        float mx = -1e30f;
        for (int le = 0; le < nsrc; ++le) mx = fmaxf(mx, scoresL[le * 8 + h]);
        float den = 0.f;
        for (int le = 0; le < nsrc; ++le) {
            float ex = __expf(scoresL[le * 8 + h] - mx);
            scoresL[le * 8 + h] = ex;
            den += ex;
        }
        denL[h] = den + 1e-16f;
    }
    __syncthreads();
    // xb[h][d] = sum_le alpha(le,h) * X[src_le][d]
    for (int p = tid; p < NHEAD * DIM; p += 256) {
        int d = p & 511, h = p >> 9;
        float acc = 0.f;
        for (int le = 0; le < nsrc; ++le)
            acc += scoresL[le * 8 + h] * ldin(X, (size_t)idxL[srcL[le]] * DIM + d, m);
        xbL[h][d] = acc / denL[h];
    }
    __syncthreads();
    // out0[c] = sum_d xb[c>>6][d]*Wgat[d][c] + b_gat[c]; write inp row
    for (int c = tid; c < DIM; c += 256) {
        int h = c >> 6;
        float acc = 0.f;
        for (int d = 0; d < DIM; ++d)
            acc += xbL[h][d] * ldin(Wgat, d * 512 + c, m);
        acc += ldin(bgat, c, m);
        float xv = ldin(X, (size_t)idxL[0] * DIM + c, m);
        if (nanf_(acc)) { atomicOr(flags, 1); acc = 0.f; }
        if (nanf_(xv))  { atomicOr(flags, 1); xv  = 0.f; }
        inp[(size_t)s * CI + DIM + c] = f2bf(acc);
        inp[(size_t)s * CI + c] = f2bf(xv);
    }
}

// ---------------------------------------------------------------------------
// MFMA GEMM #1: A1 = inp @ [Wz1|Wr1|W1] (+ bW1+bU1 on W1 part). fp32 out.
// ---------------------------------------------------------------------------
__global__ __launch_bounds__(256) void gemm_a1(
    const u16* __restrict__ A, const u16* __restrict__ BT,
    const void* __restrict__ bW1, const void* __restrict__ bU1,
    float* __restrict__ C, const int* __restrict__ modep, int* __restrict__ flags) {
    const int m = *modep;
    const int K = CI;
    int tid = threadIdx.x, wave = tid >> 6, lane = tid & 63;
    int mw = wave & 1, nw = wave >> 1, l15 = lane & 15, q = lane >> 4;
    int mbase = blockIdx.y * 64 + mw * 32;
    int nbase = blockIdx.x * 128 + nw * 64;
    f32x4 acc[2][4];
#pragma unroll
    for (int mi = 0; mi < 2; ++mi)
#pragma unroll
        for (int ni = 0; ni < 4; ++ni) acc[mi][ni] = (f32x4){0.f, 0.f, 0.f, 0.f};
    for (int k0 = 0; k0 < K; k0 += 32) {
        s16x8 a[2], b[4];
#pragma unroll
        for (int mi = 0; mi < 2; ++mi)
            a[mi] = *(const s16x8*)(A + (size_t)(mbase + mi * 16 + l15) * K + k0 + q * 8);
#pragma unroll
        for (int ni = 0; ni < 4; ++ni)
            b[ni] = *(const s16x8*)(BT + (size_t)(nbase + ni * 16 + l15) * K + k0 + q * 8);
#pragma unroll
        for (int mi = 0; mi < 2; ++mi)
#pragma unroll
            for (int ni = 0; ni < 4; ++ni)
                acc[mi][ni] = __builtin_amdgcn_mfma_f32_16x16x32_bf16(a[mi], b[ni], acc[mi][ni], 0, 0, 0);
    }
#pragma unroll
    for (int mi = 0; mi < 2; ++mi)
#pragma unroll
        for (int r = 0; r < 4; ++r) {
            int row = mbase + mi * 16 + q * 4 + r;
#pragma unroll
            for (int ni = 0; ni < 4; ++ni) {
                int col = nbase + ni * 16 + l15;
                float v = acc[mi][ni][r];
                if (col >= 1024) v += ldin(bW1, col - 1024, m) + ldin(bU1, col - 1024, m);
                if (nanf_(v)) { atomicOr(flags, 2); v = 0.f; }
                C[(size_t)row * NV3 + col] = v;
            }
        }
}

// ---------------------------------------------------------------------------
// Persistent GRU scan. 64 WGs x 256 threads.
// R6: no barriers — epoch-tagged u64 exchange; consumers poll the data.
// Tag protocol (proved overwrite-safe by the g1-gating chain):
//   g1buf[(t)&1]  : tag t   (stored phase B of t-1, consumed phase A of t)
//   g2buf[(t+1)&1]: tag t (t>=2; else 0 from memset)
//   r1g/r2g       : tag t   (stored phase A of t, consumed phase B of t)
// ---------------------------------------------------------------------------
__global__ __launch_bounds__(256) void scan_kernel(
    const float* __restrict__ A1, const u16* __restrict__ wsT,
    const void* __restrict__ bW2, const void* __restrict__ bU2,
    u64* __restrict__ g1buf, u64* __restrict__ g2buf,
    u64* __restrict__ r1g, u64* __restrict__ r2g,
    u16* __restrict__ H2,
    const int* __restrict__ modep, int* __restrict__ flags) {
    const int m_ = *modep;
    const int wg = blockIdx.x;
    const int tid = threadIdx.x;
    const int jj = tid & 7, g = tid >> 3;
    const int j0 = wg * 8;
    const int lane = tid & 63, wave = tid >> 6;

    __shared__ float g1c[512], g2c[512], rbuf[512];
    __shared__ float red[4][7][8];
    __shared__ float z1loc[8], z2loc[8], pW2loc[8], bsum[8];

    if (tid < 8) bsum[tid] = ldin(bW2, j0 + tid, m_) + ldin(bU2, j0 + tid, m_);

    // loop-invariant weights -> registers. Thread (jj,g) needs rows (m,j0+jj),
    // cols g*16..g*16+15 of each of the 7 matrices, plus U1/U2 fragments.
    u16x8 wreg[14];
#pragma unroll
    for (int m = 0; m < 7; ++m) {
        const u16* src = wsT + (size_t)m * 262144 + (size_t)(j0 + jj) * 512 + g * 16;
        wreg[2 * m]     = *(const u16x8*)src;
        wreg[2 * m + 1] = *(const u16x8*)(src + 8);
    }
    const u16* u1col = wsT + (size_t)7 * 262144 + (size_t)(j0 + jj) * 512;
    const u16* u2col = wsT + (size_t)8 * 262144 + (size_t)(j0 + jj) * 512;
    const u16x8 u1w0 = *(const u16x8*)(u1col + g * 16);
    const u16x8 u1w1 = *(const u16x8*)(u1col + g * 16 + 8);
    const u16x8 u2w0 = *(const u16x8*)(u2col + g * 16);
    const u16x8 u2w1 = *(const u16x8*)(u2col + g * 16 + 8);
    __syncthreads();

    for (int t = 0; t <= TSTEPS; ++t) {
        // prefetch this step's A1 values (independent of exchange)
        float azv = 0.f, arv = 0.f, awk = 0.f;
        if (tid < 8 && t < TSTEPS) {
            const float* a1p = A1 + (size_t)t * NV3 + j0 + tid;
            azv = a1p[0]; arv = a1p[512]; awk = a1p[1024];
        }
        // ---- phase A: poll h-states, 7-matvec, gates ----
        {
            const unsigned int eg1 = (unsigned int)t;
            const unsigned int eg2 = (t >= 2) ? (unsigned int)t : 0u;
            u64* p1 = g1buf + (size_t)(t & 1) * 512 + 2 * tid;
            u64* p2 = g2buf + (size_t)((t + 1) & 1) * 512 + 2 * tid;
            u64 x0, x1, y0, y1;
            for (;;) {
                x0 = AL64(p1); x1 = AL64(p1 + 1);
                y0 = AL64(p2); y1 = AL64(p2 + 1);
                if (tagof(x0) == eg1 && tagof(x1) == eg1 &&
                    tagof(y0) == eg2 && tagof(y1) == eg2) break;
                __builtin_amdgcn_s_sleep(1);
            }
            g1c[2 * tid] = tagval(x0); g1c[2 * tid + 1] = tagval(x1);
            g2c[2 * tid] = tagval(y0); g2c[2 * tid + 1] = tagval(y1);
        }
        __syncthreads();
        // h-state slices to registers (reused by both phases)
        float x1r[16], x2r[16];
#pragma unroll
        for (int u4 = 0; u4 < 4; ++u4) {
            f32x4 a = *(const f32x4*)&g1c[g * 16 + u4 * 4];
            f32x4 b = *(const f32x4*)&g2c[g * 16 + u4 * 4];
#pragma unroll
            for (int k = 0; k < 4; ++k) { x1r[u4 * 4 + k] = a[k]; x2r[u4 * 4 + k] = b[k]; }
        }
        {
            float p[7] = {0.f, 0.f, 0.f, 0.f, 0.f, 0.f, 0.f};
#pragma unroll
            for (int m = 0; m < 7; ++m) {
#pragma unroll
                for (int u = 0; u < 8; ++u)
                    p[m] = fmaf((m < 5) ? x1r[u] : x2r[u], bf2f(wreg[2 * m][u]), p[m]);
#pragma unroll
                for (int u = 0; u < 8; ++u)
                    p[m] = fmaf((m < 5) ? x1r[8 + u] : x2r[8 + u], bf2f(wreg[2 * m + 1][u]), p[m]);
            }
#pragma unroll
            for (int m = 0; m < 7; ++m) {
                float v = p[m];
                v += __shfl_xor(v, 8); v += __shfl_xor(v, 16); v += __shfl_xor(v, 32);
                if (lane < 8) red[wave][m][lane] = v;
            }
        }
        __syncthreads();
        if (tid < 8) {
            // r-gates first: they are the cross-WG critical path
            float s1 = red[0][1][tid] + red[1][1][tid] + red[2][1][tid] + red[3][1][tid];
            float s3 = red[0][3][tid] + red[1][3][tid] + red[2][3][tid] + red[3][3][tid];
            float s6 = red[0][6][tid] + red[1][6][tid] + red[2][6][tid] + red[3][6][tid];
            int j = j0 + tid;
            if (t < TSTEPS)
                AS64(&r1g[j], packtag(sigmoidf_(arv + s1), (unsigned int)t));
            if (t >= 1)
                AS64(&r2g[j], packtag(sigmoidf_(s3 + s6), (unsigned int)t));
            float s0 = red[0][0][tid] + red[1][0][tid] + red[2][0][tid] + red[3][0][tid];
            float s2 = red[0][2][tid] + red[1][2][tid] + red[2][2][tid] + red[3][2][tid];
            float s4 = red[0][4][tid] + red[1][4][tid] + red[2][4][tid] + red[3][4][tid];
            float s5 = red[0][5][tid] + red[1][5][tid] + red[2][5][tid] + red[3][5][tid];
            if (t < TSTEPS) z1loc[tid] = sigmoidf_(azv + s0);
            if (t >= 1) { z2loc[tid] = sigmoidf_(s2 + s5); pW2loc[tid] = s4; }
        }
        // ---- phase B: poll r-gates, U-matvecs, state update ----
        {
            const unsigned int er = (unsigned int)t;
            const bool need1 = (t < TSTEPS), need2 = (t >= 1);
            u64* q1 = r1g + 2 * tid;
            u64* q2 = r2g + 2 * tid;
            u64 x0 = 0, x1 = 0, y0 = 0, y1 = 0;
            for (;;) {
                if (need1) { x0 = AL64(q1); x1 = AL64(q1 + 1); }
                if (need2) { y0 = AL64(q2); y1 = AL64(q2 + 1); }
                bool ok = true;
                if (need1) ok = ok && (tagof(x0) == er) && (tagof(x1) == er);
                if (need2) ok = ok && (tagof(y0) == er) && (tagof(y1) == er);
                if (ok) break;
                __builtin_amdgcn_s_sleep(1);
            }
            if (need1) {
                rbuf[2 * tid] = tagval(x0); rbuf[2 * tid + 1] = tagval(x1);
                __syncthreads();
                float pa = 0.f;
#pragma unroll
                for (int u4 = 0; u4 < 4; ++u4) {
                    f32x4 rr = *(const f32x4*)&rbuf[g * 16 + u4 * 4];
#pragma unroll
                    for (int k = 0; k < 4; ++k) {
                        const int u = u4 * 4 + k;
                        const float wv = bf2f((u < 8) ? u1w0[u] : u1w1[u - 8]);
                        pa = fmaf(rr[k] * x1r[u], wv, pa);
                    }
                }
                pa += __shfl_xor(pa, 8); pa += __shfl_xor(pa, 16); pa += __shfl_xor(pa, 32);
                if (lane < 8) red[wave][0][lane] = pa;
                __syncthreads();
                if (tid < 8) {
                    float s = red[0][0][tid] + red[1][0][tid] + red[2][0][tid] + red[3][0][tid];
                    int j = j0 + tid;
                    float ht1 = tanhf(awk + s);
                    float z = z1loc[tid], g1v = g1c[j];
                    float g1n = z * ht1 + (1.f - z) * g1v;
                    if (nanf_(g1n)) { atomicOr(flags, 4); g1n = 0.f; }
                    AS64(&g1buf[(size_t)((t + 1) & 1) * 512 + j], packtag(g1n, (unsigned int)(t + 1)));
                }
            }
            if (need2) {
                __syncthreads();
                rbuf[2 * tid] = tagval(y0); rbuf[2 * tid + 1] = tagval(y1);
                __syncthreads();
                float pa = 0.f;
#pragma unroll
                for (int u4 = 0; u4 < 4; ++u4) {
                    f32x4 rr = *(const f32x4*)&rbuf[g * 16 + u4 * 4];
#pragma unroll
                    for (int k = 0; k < 4; ++k) {
                        const int u = u4 * 4 + k;
                        const float wv = bf2f((u < 8) ? u2w0[u] : u2w1[u - 8]);
                        pa = fmaf(rr[k] * x2r[u], wv, pa);
                    }
                }
                pa += __shfl_xor(pa, 8); pa += __shfl_xor(pa, 16); pa += __shfl_xor(pa, 32);
                if (lane < 8) red[wave][1][lane] = pa;
                __syncthreads();
                if (tid < 8) {
                    float s = red[0][1][tid] + red[1][1][tid] + red[2][1][tid] + red[3][1][tid];
                    int j = j0 + tid;
                    float ht2 = tanhf(pW2loc[tid] + bsum[tid] + s);
                    float z = z2loc[tid], g2v = g2c[j];
                    float g2n = z * ht2 + (1.f - z) * g2v;
                    if (nanf_(g2n)) { atomicOr(flags, 4); g2n = 0.f; }
                    AS64(&g2buf[(size_t)(t & 1) * 512 + j], packtag(g2n, (unsigned int)(t + 1)));
                    H2[(size_t)(t - 1) * 512 + j] = f2bf(g2n);
                }
            }
        }
    }
}

// ---------------------------------------------------------------------------
// MFMA GEMM #2: logits = H2 @ Wg + bg -> d_out (mode dtype), + row exp-sums.
// ---------------------------------------------------------------------------
__global__ __launch_bounds__(256) void gemm_logits(
    const u16* __restrict__ H2, const void* __restrict__ Wg,
    const void* __restrict__ bg, void* __restrict__ out,
    float* __restrict__ rowsum, const int* __restrict__ modep, int* __restrict__ flags) {
    const int m = *modep;
    const int K = DIM;
    int tid = threadIdx.x, wave = tid >> 6, lane = tid & 63;
    int mw = wave & 1, nw = wave >> 1, l15 = lane & 15, q = lane >> 4;
    int mbase = blockIdx.y * 64 + mw * 32;
    int nbase = blockIdx.x * 128 + nw * 64;
    f32x4 acc[2][4];
#pragma unroll
    for (int mi = 0; mi < 2; ++mi)
#pragma unroll
        for (int ni = 0; ni < 4; ++ni) acc[mi][ni] = (f32x4){0.f, 0.f, 0.f, 0.f};
    for (int k0 = 0; k0 < K; k0 += 32) {
        s16x8 a[2], b[4];
#pragma unroll
        for (int mi = 0; mi < 2; ++mi)
            a[mi] = *(const s16x8*)(H2 + (size_t)(mbase + mi * 16 + l15) * K + k0 + q * 8);
#pragma unroll
        for (int ni = 0; ni < 4; ++ni) {
            int n = nbase + ni * 16 + l15;
            if (n >= VOC) n = VOC - 1;
            size_t kb = (size_t)(k0 + q * 8) * VOC + n;
#pragma unroll
            for (int j = 0; j < 8; ++j) b[ni][j] = (short)f2bf(ldin(Wg, kb + (size_t)j * VOC, m));
        }
#pragma unroll
        for (int mi = 0; mi < 2; ++mi)
#pragma unroll
            for (int ni = 0; ni < 4; ++ni)
                acc[mi][ni] = __builtin_amdgcn_mfma_f32_16x16x32_bf16(a[mi], b[ni], acc[mi][ni], 0, 0, 0);
    }
    __shared__ float lds_rows[64];
    if (tid < 64) lds_rows[tid] = 0.f;
    __syncthreads();
#pragma unroll
    for (int mi = 0; mi < 2; ++mi)
#pragma unroll
        for (int r = 0; r < 4; ++r) {
            int row = mbase + mi * 16 + q * 4 + r;
            float esum = 0.f;
#pragma unroll
            for (int ni = 0; ni < 4; ++ni) {
                int col = nbase + ni * 16 + l15;
                float v = acc[mi][ni][r];
                if (col < VOC) {
                    v += ldin(bg, col, m);
                    if (nanf_(v)) { atomicOr(flags, 8); v = 0.f; }
                    if (m) ((float*)out)[(size_t)row * VOC + col] = v;
                    else   ((u16*)out)[(size_t)row * VOC + col] = f2bf(v);
                    esum += __expf(v);
                }
            }
            esum += __shfl_xor(esum, 1); esum += __shfl_xor(esum, 2);
            esum += __shfl_xor(esum, 4); esum += __shfl_xor(esum, 8);
            if (l15 == 0) atomicAdd(&lds_rows[row - blockIdx.y * 64], esum);
        }
    __syncthreads();
    if (tid < 64) atomicAdd(&rowsum[blockIdx.y * 64 + tid], lds_rows[tid]);
}

// ---------------------------------------------------------------------------
// in-place: out = logit - log(rowsum[row]); out[0] += 1000*stage if NaN seen.
// ---------------------------------------------------------------------------
__global__ __launch_bounds__(256) void logsoftmax_fix(void* __restrict__ out,
                                                      const float* __restrict__ rowsum,
                                                      const int* __restrict__ modep,
                                                      int* __restrict__ flags) {
    const int m = *modep;
    int row = blockIdx.y;
    int c0 = blockIdx.x * 2048 + threadIdx.x * 8;
    if (c0 >= VOC) return;
    float rs = rowsum[row];
    float ls = logf(rs);
    if (nanf_(ls) || !(rs > 0.f)) { atomicOr(flags, 16); ls = 0.f; }
    float sentinel = 0.f;
    if (row == 0 && c0 == 0) {
        int f = *flags;
        if (f) sentinel = 1000.f * (float)__ffs(f);
    }
    size_t base = (size_t)row * VOC + c0;
    if (m) {
        float* o = (float*)out;
        int lim = (c0 + 8 <= VOC) ? 8 : (VOC - c0);
        for (int i = 0; i < lim; ++i) {
            float v = o[base + i] - ls;
            if (i == 0) v += sentinel;
            o[base + i] = v;
        }
    } else {
        u16* o = (u16*)out;
        int lim = (c0 + 8 <= VOC) ? 8 : (VOC - c0);
        for (int i = 0; i < lim; ++i) {
            float v = bf2f(o[base + i]) - ls;
            if (i == 0) v += sentinel;
            o[base + i] = f2bf(v);
        }
    }
}

// ---------------------------------------------------------------------------
extern "C" void kernel_launch(void* const* d_in, const int* in_sizes, int n_in,
                              void* d_out, int out_size, void* d_ws, size_t ws_size,
                              hipStream_t stream) {
    const int* xidx = (const int*)d_in[0];
    const int* eidx = (const int*)d_in[1];
    const void* X    = d_in[2];
    const void* Wgat = d_in[3];
    const void* asrc = d_in[4];
    const void* adst = d_in[5];
    const void* bgat = d_in[6];
    const void* Wz1  = d_in[7];
    const void* Uz1  = d_in[8];
    const void* Wr1  = d_in[9];
    const void* Ur1  = d_in[10];
    const void* W1   = d_in[11];
    const void* bW1  = d_in[12];
    const void* U1   = d_in[13];
    const void* bU1  = d_in[14];
    const void* Wz2  = d_in[15];
    const void* Uz2  = d_in[16];
    const void* Wr2  = d_in[17];
    const void* Ur2  = d_in[18];
    const void* W2   = d_in[19];
    const void* bW2  = d_in[20];
    const void* U2   = d_in[21];
    const void* bU2  = d_in[22];
    const void* Wg   = d_in[23];
    const void* bg   = d_in[24];

    char* ws = (char*)d_ws;
    int*   modep  = (int*)(ws + OFF_MODE);
    int*   flags  = (int*)(ws + OFF_FLAGS);
    float* rowsum = (float*)(ws + OFF_ROWSUM);
    u64*   g1buf  = (u64*)(ws + OFF_G1);
    u64*   g2buf  = (u64*)(ws + OFF_G2);
    u64*   r1g    = (u64*)(ws + OFF_R1);
    u64*   r2g    = (u64*)(ws + OFF_R2);
    float* WAs    = (float*)(ws + OFF_WAS);
    float* WAd    = (float*)(ws + OFF_WAD);
    u16*   inp    = (u16*)(ws + OFF_INP);
    float* A1     = (float*)(ws + OFF_A1);
    u16*   H2     = (u16*)(ws + OFF_H2);
    u16*   wsT    = (u16*)(ws + OFF_WST);
    u16*   WcatT  = (u16*)(ws + OFF_WCATT);

    hipMemsetAsync(ws, 0, ZERO_BYTES, stream);

    detect_mode<<<1, 64, 0, stream>>>(X, modep);

    prep_att<<<32, 256, 0, stream>>>(Wgat, asrc, adst, WAs, WAd, modep);

    Ptrs9 p9; // order: Uz1,Ur1,Wz2,Wr2,W2,Uz2,Ur2,U1,U2
    p9.p[0] = Uz1; p9.p[1] = Ur1; p9.p[2] = Wz2; p9.p[3] = Wr2; p9.p[4] = W2;
    p9.p[5] = Uz2; p9.p[6] = Ur2; p9.p[7] = U1;  p9.p[8] = U2;
    transpose9<<<dim3(16, 16, 9), 256, 0, stream>>>(p9, wsT, modep);

    Ptrs3 p3; p3.p[0] = Wz1; p3.p[1] = Wr1; p3.p[2] = W1;
    transpose3<<<dim3(16, 32, 3), 256, 0, stream>>>(p3, WcatT, modep);

    gat_kernel<<<S_SEQ, 256, 0, stream>>>(xidx, eidx, X, Wgat, WAs, WAd, bgat, inp, modep, flags);

    gemm_a1<<<dim3(NV3 / 128, S_SEQ / 64), 256, 0, stream>>>(inp, WcatT, bW1, bU1, A1, modep, flags);

    scan_kernel<<<KWG, 256, 0, stream>>>(A1, wsT, bW2, bU2, g1buf, g2buf, r1g, r2g, H2, modep, flags);

    gemm_logits<<<dim3((VOC + 127) / 128, S_SEQ / 64), 256, 0, stream>>>(H2, Wg, bg, d_out, rowsum, modep, flags);

    logsoftmax_fix<<<dim3(25, S_SEQ), 256, 0, stream>>>(d_out, rowsum, modep, flags);
}